// Round 1
// baseline (1123.320 us; speedup 1.0000x reference)
//
#include <hip/hip_runtime.h>

#define USER_NUM 200000
#define ITEM_NUM 100000
#define N_NODES  300000   // USER_NUM + ITEM_NUM
#define EMB      64
#define N_EDGES  4800000
#define N_LAYERS 3

#define SCAN_CHUNK 2048   // elements per scan1 block (256 thr x 8)
#define SCAN_NB    ((N_NODES + SCAN_CHUNK - 1) / SCAN_CHUNK)  // 147

// 16 stripes, two y-phases of 8. stripe = (blockIdx.x & 7) | (y<<3):
// consecutive blockIdx.x round-robin across the 8 XCDs, so stripe k's
// scattered writes are issued only from XCD (k&7) -> its 2.4 MB CSR
// window accumulates full 64B lines in THAT XCD's 4 MB L2 before one
// eviction (fixes the 8x write amplification seen with cross-XCD stripes).
#define N_STRIPES     16
#define STRIPE_NODES  (N_NODES / N_STRIPES)   // 18750

// ---------------- CSR build (runs every call) ------------------------------

// Histogram + per-edge rank within its row (atomicAdd return value).
__global__ __launch_bounds__(256) void hist_kernel(
    const int* __restrict__ esrc, int* __restrict__ cnt,
    int* __restrict__ rank)
{
    int e = blockIdx.x * blockDim.x + threadIdx.x;
    if (e >= N_EDGES) return;
    rank[e] = atomicAdd(&cnt[esrc[e]], 1);
}

// Exclusive scan, stage 1: per-block scan of SCAN_CHUNK elements.
__global__ __launch_bounds__(256) void scan1_kernel(
    const int* __restrict__ cnt, int* __restrict__ rowptr,
    int* __restrict__ blockSums)
{
    __shared__ int lds[256];
    int base = blockIdx.x * SCAN_CHUNK + threadIdx.x * 8;
    int v[8];
    int s = 0;
    #pragma unroll
    for (int i = 0; i < 8; ++i) {
        int idx = base + i;
        v[i] = (idx < N_NODES) ? cnt[idx] : 0;
        s += v[i];
    }
    lds[threadIdx.x] = s;
    __syncthreads();
    for (int off = 1; off < 256; off <<= 1) {
        int t = (threadIdx.x >= off) ? lds[threadIdx.x - off] : 0;
        __syncthreads();
        lds[threadIdx.x] += t;
        __syncthreads();
    }
    int excl = (threadIdx.x == 0) ? 0 : lds[threadIdx.x - 1];
    if (threadIdx.x == 255) blockSums[blockIdx.x] = lds[255];
    int run = excl;
    #pragma unroll
    for (int i = 0; i < 8; ++i) {
        int idx = base + i;
        if (idx < N_NODES) rowptr[idx] = run;
        run += v[i];
    }
}

// Stage 2: exclusive-scan the (147) block sums in-place, single block.
__global__ __launch_bounds__(256) void scan2_kernel(int* __restrict__ blockSums, int nb)
{
    __shared__ int lds[256];
    int v = (threadIdx.x < nb) ? blockSums[threadIdx.x] : 0;
    lds[threadIdx.x] = v;
    __syncthreads();
    for (int off = 1; off < 256; off <<= 1) {
        int t = (threadIdx.x >= off) ? lds[threadIdx.x - off] : 0;
        __syncthreads();
        lds[threadIdx.x] += t;
        __syncthreads();
    }
    int excl = (threadIdx.x == 0) ? 0 : lds[threadIdx.x - 1];
    if (threadIdx.x < nb) blockSums[threadIdx.x] = excl;
}

// Stage 3: add block offsets; write rowptr[N] = E. (No cursor init needed —
// scatter placement is rank-based, atomic-free.)
__global__ __launch_bounds__(256) void scan3_kernel(
    int* __restrict__ rowptr, const int* __restrict__ blockSums)
{
    int idx = blockIdx.x * blockDim.x + threadIdx.x;
    if (idx > N_NODES) return;
    if (idx == N_NODES) { rowptr[N_NODES] = N_EDGES; return; }
    rowptr[idx] = rowptr[idx] + blockSums[idx / SCAN_CHUNK];
}

// Atomic-free striped permute. Placement p = rowptr[s] + rank[e] is unique
// by construction. Stripe-to-XCD pinning via (blockIdx.x & 7); the two
// y-phases keep only 8 stripes (2.4 MB window each) live at a time.
__global__ __launch_bounds__(256) void scatter_kernel(
    const int* __restrict__ esrc, const int* __restrict__ edst,
    const float* __restrict__ eval, const int* __restrict__ rank,
    const int* __restrict__ rowptr, int2* __restrict__ edges_s)
{
    int chunk  = blockIdx.x >> 3;
    int stripe = (blockIdx.x & 7) | (blockIdx.y << 3);
    int e = chunk * 256 + threadIdx.x;
    if (e >= N_EDGES) return;
    int s = esrc[e];
    int lo = stripe * STRIPE_NODES;
    if ((unsigned)(s - lo) >= (unsigned)STRIPE_NODES) return;
    int p = rowptr[s] + rank[e];
    edges_s[p] = make_int2(edst[e], __float_as_int(eval[e]));
}

// ---------------- CSR SpMM: one wave per row, lane = column -----------------
// y[row][lane] = sum_e val_e * x[dst_e][lane];  acc += y/3 fused.
// Edge (dst,val) broadcast via readlane -> SGPRs; 16 gather loads in flight
// per group (deg ~Poisson(16), so one group usually covers the row).
__global__ __launch_bounds__(256) void spmm_csr(
    const int2*  __restrict__ edges_s,
    const int*   __restrict__ rowptr,
    const float* __restrict__ userp,
    const float* __restrict__ itemp,
    float*       __restrict__ y,
    float*       __restrict__ acc,
    int layer)
{
    int wid  = __builtin_amdgcn_readfirstlane(
                   (int)((blockIdx.x * blockDim.x + threadIdx.x) >> 6));
    int lane = threadIdx.x & 63;
    if (wid >= N_NODES) return;

    int start = rowptr[wid];
    int end   = rowptr[wid + 1];

    float a0 = 0.0f, a1 = 0.0f;
    for (int base = start; base < end; base += 64) {
        int m = end - base;
        if (m > 64) m = 64;
        // each lane owns one edge of this chunk; padded lanes contribute v=0
        int2 e = (lane < m) ? edges_s[base + lane] : make_int2(0, 0);
        int groups = (m + 15) >> 4;
        for (int g = 0; g < groups; ++g) {
            int j = g << 4;
            float p[16], vv[16];
            #pragma unroll
            for (int k = 0; k < 16; ++k) {
                int d  = __builtin_amdgcn_readlane(e.x, j + k);   // scalar
                vv[k]  = __int_as_float(__builtin_amdgcn_readlane(e.y, j + k));
                const float* row = (d < USER_NUM)
                                 ? (userp + (size_t)d * EMB)
                                 : (itemp + (size_t)(d - USER_NUM) * EMB);
                p[k] = row[lane];   // 16 independent coalesced 256B wave reads
            }
            #pragma unroll
            for (int k = 0; k < 16; k += 2) {
                a0 += vv[k]     * p[k];
                a1 += vv[k + 1] * p[k + 1];
            }
        }
    }

    float a = a0 + a1;
    size_t o = (size_t)wid * EMB + lane;
    if (layer < N_LAYERS - 1) y[o] = a;   // last layer's y is never read
    float t = a * (1.0f / (float)N_LAYERS);
    if (layer == 0) acc[o] = t;           // first layer: pure write
    else            acc[o] += t;
}

// ---------------------------------------------------------------------------

extern "C" void kernel_launch(void* const* d_in, const int* in_sizes, int n_in,
                              void* d_out, int out_size, void* d_ws, size_t ws_size,
                              hipStream_t stream)
{
    const float* user_emb = (const float*)d_in[0];
    const float* item_emb = (const float*)d_in[1];
    const float* edge_val = (const float*)d_in[2];
    const int*   edge_src = (const int*)  d_in[3];
    const int*   edge_dst = (const int*)  d_in[4];
    float* out = (float*)d_out;

    const size_t node_bytes = (size_t)N_NODES * EMB * sizeof(float);  // 76.8 MB

    char* ws = (char*)d_ws;
    float* buf0     = (float*)ws;                 ws += node_bytes;
    float* buf1     = (float*)ws;                 ws += node_bytes;
    int2*  edges_s  = (int2*)ws;                  ws += (size_t)N_EDGES * 8;
    int*   rowptr   = (int*)ws;                   ws += (size_t)(N_NODES + 1) * 4;
    int*   cnt      = (int*)ws;                   ws += (size_t)N_NODES * 4;
    int*   blockSum = (int*)ws;                   ws += SCAN_NB * 4;

    // rank[] (19.2 MB) aliases buf0: hist writes it, scatter reads it, and
    // buf0 is first written by spmm layer 0 -- strictly after scatter.
    int* rank = (int*)buf0;

    // ---- CSR build ----
    hipMemsetAsync(cnt, 0, (size_t)N_NODES * 4, stream);
    const int eb = (N_EDGES + 255) / 256;
    hist_kernel <<<eb, 256, 0, stream>>>(edge_src, cnt, rank);
    scan1_kernel<<<SCAN_NB, 256, 0, stream>>>(cnt, rowptr, blockSum);
    scan2_kernel<<<1, 256, 0, stream>>>(blockSum, SCAN_NB);
    scan3_kernel<<<(N_NODES + 1 + 255) / 256, 256, 0, stream>>>(rowptr, blockSum);
    scatter_kernel<<<dim3(eb * 8, 2), 256, 0, stream>>>(
        edge_src, edge_dst, edge_val, rank, rowptr, edges_s);

    // ---- 3 SpMM layers, axpy fused ----
    const int spmm_blocks = (N_NODES * 64 + 255) / 256;   // 1 wave/row
    spmm_csr<<<spmm_blocks, 256, 0, stream>>>(edges_s, rowptr,
                                              user_emb, item_emb,
                                              buf0, out, 0);
    spmm_csr<<<spmm_blocks, 256, 0, stream>>>(edges_s, rowptr,
                                              buf0, buf0 + (size_t)USER_NUM * EMB,
                                              buf1, out, 1);
    spmm_csr<<<spmm_blocks, 256, 0, stream>>>(edges_s, rowptr,
                                              buf1, buf1 + (size_t)USER_NUM * EMB,
                                              buf0, out, 2);
}